// Round 7
// baseline (423.475 us; speedup 1.0000x reference)
//
#include <hip/hip_runtime.h>

// CRF forward-score + gold-score, MI355X (gfx950).
//
// R11 = R10 with the compile fix: __builtin_amdgcn_cvt_pkrtz returns a
// __fp16 ext-vector (clang builtin 'h') which won't convert to _Float16
// vectors (MFMA builtins use 'x'). pack_w now splits via scalar (f16)
// casts + exact f32 subtraction (two-term split; val-(float)hi is exact,
// ~21-22 effective bits). No algorithmic change vs R10.
//
// R10: MFMA RECURRENCE. Vector-pipe formulations (R4-R9) floor at
// ~300-400 VALU-cyc per chain-step for the 64x64 matvec; MfmaUtil was 0.0
// all session. Batch 16 chains (columns) per wave and run
//   z[64x16] = E[64x64] * beta[64x16]
// on the matrix pipe: 4 row-tiles x 2 K-slabs of mfma_f32_16x16x32_f16,
// with SPLIT-F16 precision recovery (E=Ehi+Elo, b=bhi+blo;
// z = Ehi*bhi + Ehi*blo + Elo*bhi -> 24 MFMA/step, err ~2^-21/step).
//
// Layout facts:
//  - C/D layout (VERIFIED, guide m89): col=lane&15, row=4*(lane>>4)+reg.
//  - A/B within-fragment k-order CANCELS: loading A and B with the SAME
//    (h,e)->k bijection contracts correctly (any shared permutation of k
//    cancels in sum_k A[r,pi(k)]B[pi(k),c]).
//  - C layout == B layout alignment: output (tau,h,r) is exactly next
//    step's B fragment (tau=2S+(e>>2), r=e&3) -> zero cross-lane movement.
//
// Per-column (=per-chain) normalization: max-exponent over the column
// (uint max on positive-float bits + shfl_xor 16,32), scale by exact
// 2^-e, exact int esum bookkeeping (proven R4 scheme). Packed values in
// [0,2) -- f16-safe.
//
// Structure: 64 blocks x 128 threads. wave0 = fwd chain (255 steps,
// t=1..255) + gold + meet; wave1 = bwd chain (256 steps, t=511..256,
// D_t applied before each E^T; telescoped as acc*g with tail matvec),
// writes y/esum to LDS. score = log(sum_k x_k y_k) + (esumA+esumB)*ln2.
// exp(u) prefetched depth-2.

#define BB 1024
#define TT 512
#define KK 64
#define START_TAG 62
#define NBLK 64
#define GB 16

typedef _Float16 f16;
typedef f16   f16x8 __attribute__((ext_vector_type(8)));
typedef float f32x4 __attribute__((ext_vector_type(4)));

union W8 { f16x8 v; f16 e[8]; };

#define MFMA16(A, B, C) __builtin_amdgcn_mfma_f32_16x16x32_f16((A), (B), (C), 0, 0, 0)

__device__ __forceinline__ f32x4 exp4(f32x4 u) {
  f32x4 r; r.x = __expf(u.x); r.y = __expf(u.y); r.z = __expf(u.z); r.w = __expf(u.w);
  return r;
}

__device__ __forceinline__ unsigned umaxu(unsigned a, unsigned b) { return a > b ? a : b; }

// per-column max-exponent normalization: v = q * 2^-e, esum += e
__device__ __forceinline__ void normalize(const f32x4 (&q)[4], f32x4 (&v)[4], int& esum) {
  unsigned mb = 0u;
  #pragma unroll
  for (int tau = 0; tau < 4; ++tau) {
    mb = umaxu(mb, __float_as_uint(q[tau].x));
    mb = umaxu(mb, __float_as_uint(q[tau].y));
    mb = umaxu(mb, __float_as_uint(q[tau].z));
    mb = umaxu(mb, __float_as_uint(q[tau].w));
  }
  mb = umaxu(mb, (unsigned)__shfl_xor((int)mb, 16));
  mb = umaxu(mb, (unsigned)__shfl_xor((int)mb, 32));
  esum += (int)(mb >> 23) - 127;
  const float s = __uint_as_float(0x7F000000u - (mb & 0x7F800000u));
  #pragma unroll
  for (int tau = 0; tau < 4; ++tau) v[tau] = q[tau] * s;
}

// split-f16 pack: v[tau][r] -> B fragments (slab S covers tau 2S,2S+1)
// element e of slab S = v[2S + (e>>2)][e&3]  (matches the A k-map below)
__device__ __forceinline__ void pack_w(const f32x4 (&v)[4], W8 (&whi)[2], W8 (&wlo)[2]) {
  #pragma unroll
  for (int S = 0; S < 2; ++S) {
    #pragma unroll
    for (int c = 0; c < 2; ++c) {
      const f32x4 t = v[2 * S + c];
      const f16 h0 = (f16)t.x, h1 = (f16)t.y, h2 = (f16)t.z, h3 = (f16)t.w;
      whi[S].e[4 * c + 0] = h0;
      whi[S].e[4 * c + 1] = h1;
      whi[S].e[4 * c + 2] = h2;
      whi[S].e[4 * c + 3] = h3;
      wlo[S].e[4 * c + 0] = (f16)(t.x - (float)h0);
      wlo[S].e[4 * c + 1] = (f16)(t.y - (float)h1);
      wlo[S].e[4 * c + 2] = (f16)(t.z - (float)h2);
      wlo[S].e[4 * c + 3] = (f16)(t.w - (float)h3);
    }
  }
}

// one recurrence step: z = E*w (24 MFMA, split-3)
__device__ __forceinline__ void mfma_step(const W8 (&Ehi)[4][2], const W8 (&Elo)[4][2],
                                          const W8 (&whi)[2], const W8 (&wlo)[2],
                                          f32x4 (&acc)[4]) {
  #pragma unroll
  for (int tau = 0; tau < 4; ++tau) {
    f32x4 a = {0.f, 0.f, 0.f, 0.f};
    a = MFMA16(Ehi[tau][0].v, whi[0].v, a);
    a = MFMA16(Ehi[tau][1].v, whi[1].v, a);
    a = MFMA16(Elo[tau][0].v, whi[0].v, a);
    a = MFMA16(Elo[tau][1].v, whi[1].v, a);
    a = MFMA16(Ehi[tau][0].v, wlo[0].v, a);
    a = MFMA16(Ehi[tau][1].v, wlo[1].v, a);
    acc[tau] = a;
  }
}

// DIR=0: fwd x = prod_{t=1..255}(D_t E) beta0   (255 MFMA-steps)
// DIR=1: bwd y = E^T D_256 ... E^T D_511 1      (256 MFMA-steps)
template <int DIR>
__device__ __forceinline__ void run_chain(const float* __restrict__ feats,
                                          const float* __restrict__ trans,
                                          int blk, int lane,
                                          f32x4 (&v)[4], int& esum) {
  const int m = lane & 15;
  const int h = lane >> 4;

  // ---- E fragments, split hi/lo. A k-map: k = 32S + 16(e>>2) + 4h + (e&3)
  W8 Ehi[4][2], Elo[4][2];
  #pragma unroll
  for (int tau = 0; tau < 4; ++tau)
    #pragma unroll
    for (int S = 0; S < 2; ++S)
      #pragma unroll
      for (int e = 0; e < 8; ++e) {
        const int kk = 32 * S + 16 * (e >> 2) + 4 * h + (e & 3);
        const int row = 16 * tau + m;
        const float val = __expf(DIR ? trans[kk * KK + row] : trans[row * KK + kk]);
        const f16 hi = (f16)val;
        Ehi[tau][S].e[e] = hi;
        Elo[tau][S].e[e] = (f16)(val - (float)hi);
      }

  const float* fB = feats + (size_t)(blk * GB + m) * TT * KK + 4 * h;

  W8 whi[2], wlo[2];
  f32x4 uN[4], g[4];
  esum = 0;

  if (DIR == 0) {
    f32x4 vv[4];
    #pragma unroll
    for (int tau = 0; tau < 4; ++tau) vv[tau] = (f32x4){0.f, 0.f, 0.f, 0.f};
    if (h == 3) vv[3].z = 1.0f;   // row 62 = 16*3 + 4*3 + 2
    pack_w(vv, whi, wlo);
    #pragma unroll
    for (int tau = 0; tau < 4; ++tau) {
      f32x4 u0 = *(const f32x4*)(fB + (size_t)1 * KK + 16 * tau);
      uN[tau]  = *(const f32x4*)(fB + (size_t)2 * KK + 16 * tau);
      g[tau] = exp4(u0);
    }
  } else {
    f32x4 q[4];
    #pragma unroll
    for (int tau = 0; tau < 4; ++tau) {
      f32x4 u0 = *(const f32x4*)(fB + (size_t)511 * KK + 16 * tau);
      uN[tau]  = *(const f32x4*)(fB + (size_t)510 * KK + 16 * tau);
      q[tau] = exp4(u0);
    }
    normalize(q, v, esum);          // w0 = pack(exp(u_511)), normalized
    pack_w(v, whi, wlo);
    #pragma unroll
    for (int tau = 0; tau < 4; ++tau) {
      g[tau] = exp4(uN[tau]);       // g for t=510
      uN[tau] = *(const f32x4*)(fB + (size_t)509 * KK + 16 * tau);
    }
  }

  for (int i = 0; i < 255; ++i) {
    f32x4 acc[4];
    mfma_step(Ehi, Elo, whi, wlo, acc);

    // prefetch u two steps ahead (fwd: 3+i <= 257; bwd: 508-i >= 254)
    const int tf = DIR ? (508 - i) : (3 + i);
    f32x4 uF[4];
    #pragma unroll
    for (int tau = 0; tau < 4; ++tau)
      uF[tau] = *(const f32x4*)(fB + (size_t)tf * KK + 16 * tau);

    f32x4 q[4];
    #pragma unroll
    for (int tau = 0; tau < 4; ++tau) q[tau] = acc[tau] * g[tau];
    normalize(q, v, esum);
    pack_w(v, whi, wlo);

    #pragma unroll
    for (int tau = 0; tau < 4; ++tau) { g[tau] = exp4(uN[tau]); uN[tau] = uF[tau]; }
  }

  if (DIR == 1) {                   // final step t=256: matvec only, no g
    f32x4 acc[4];
    mfma_step(Ehi, Elo, whi, wlo, acc);
    normalize(acc, v, esum);
  }
}

__global__ __launch_bounds__(128, 1) void crf_mfma_kernel(
    const float* __restrict__ feats,   // [B, T, K]
    const int*   __restrict__ tags,    // [B, T]
    const float* __restrict__ trans,   // [K, K]  trans[i*K+j] = score j -> i
    float*       __restrict__ diff)    // [B]  forward - gold
{
  const int lane = threadIdx.x & 63;
  const int wv   = threadIdx.x >> 6;
  const int blk  = blockIdx.x;
  const int m = lane & 15;
  const int h = lane >> 4;

  __shared__ float ysh[KK][GB];
  __shared__ int   esum_sh[GB];

  f32x4 v[4];
  int esum;

  if (wv == 1) {
    run_chain<1>(feats, trans, blk, lane, v, esum);
    #pragma unroll
    for (int tau = 0; tau < 4; ++tau) {
      ysh[16 * tau + 4 * h + 0][m] = v[tau].x;
      ysh[16 * tau + 4 * h + 1][m] = v[tau].y;
      ysh[16 * tau + 4 * h + 2][m] = v[tau].z;
      ysh[16 * tau + 4 * h + 3][m] = v[tau].w;
    }
    if (lane < 16) esum_sh[lane] = esum;
    __syncthreads();
  } else {
    run_chain<0>(feats, trans, blk, lane, v, esum);

    // ---- gold path score: lane (m,h) covers tt = 1+h, stride 4
    const int bglob = blk * GB + m;
    const int* tg = tags + bglob * TT;
    const float* fg = feats + (size_t)bglob * TT * KK;
    float gs = 0.f;
    #pragma unroll 8
    for (int tt = 1 + h; tt < TT; tt += 4) {
      const int tc = tg[tt];
      const int tp = tg[tt - 1];
      gs += trans[tc * KK + tp] + fg[(size_t)tt * KK + tc];
    }
    gs += __shfl_xor(gs, 16);
    gs += __shfl_xor(gs, 32);

    __syncthreads();

    // ---- meet: p_b = sum_k x[k,b] * y[k,b]
    float p = 0.f;
    #pragma unroll
    for (int tau = 0; tau < 4; ++tau) {
      p += v[tau].x * ysh[16 * tau + 4 * h + 0][m];
      p += v[tau].y * ysh[16 * tau + 4 * h + 1][m];
      p += v[tau].z * ysh[16 * tau + 4 * h + 2][m];
      p += v[tau].w * ysh[16 * tau + 4 * h + 3][m];
    }
    p += __shfl_xor(p, 16);
    p += __shfl_xor(p, 32);

    if (lane < 16)
      diff[blk * GB + lane] =
          __logf(p) + (float)(esum + esum_sh[lane]) * 0.6931471805599453f - gs;
  }
}

__global__ __launch_bounds__(1024) void reduce_mean_kernel(
    const float* __restrict__ diff, float* __restrict__ out)
{
  __shared__ float part[16];
  const int tid = threadIdx.x;
  float v = diff[tid];
  #pragma unroll
  for (int off = 32; off; off >>= 1) v += __shfl_xor(v, off);
  if ((tid & 63) == 0) part[tid >> 6] = v;
  __syncthreads();
  if (tid < 16) {
    float s = part[tid];
    #pragma unroll
    for (int off = 8; off; off >>= 1) s += __shfl_xor(s, off);
    if (tid == 0) out[0] = s * (1.0f / 1024.0f);
  }
}

extern "C" void kernel_launch(void* const* d_in, const int* in_sizes, int n_in,
                              void* d_out, int out_size, void* d_ws, size_t ws_size,
                              hipStream_t stream) {
  const float* feats = (const float*)d_in[0];
  const int*   tags  = (const int*)d_in[1];
  const float* trans = (const float*)d_in[2];
  float* out  = (float*)d_out;
  float* diff = (float*)d_ws;   // 1024 floats of scratch

  crf_mfma_kernel<<<dim3(NBLK), dim3(128), 0, stream>>>(feats, tags, trans, diff);
  reduce_mean_kernel<<<dim3(1), dim3(1024), 0, stream>>>(diff, out);
}

// Round 8
// 296.048 us; speedup vs baseline: 1.4304x; 1.4304x over previous
//
#include <hip/hip_runtime.h>

// CRF forward-score + gold-score, MI355X (gfx950).
//
// R12 = R11 + DEEP FEAT PIPELINE. R11 (MFMA recurrence, verified absmax
// 0.0) ran 285 us/kernel = 2670 cyc/step, but compute is only ~400 cyc:
// Occupancy 1.47% (128 waves machine-wide, 2 waves/CU on 64 CUs) means
// NO TLP to hide the ~900-cyc HBM latency of the per-step feat loads,
// and the old uN/uF prefetch gave only 1 window of slack. Counters:
// hbm 349 GB/s (4% peak, latency- not BW-bound), FETCH = one clean pass.
//
// Fix: register ring uR[5][4] (255 = 5*51 so ring indices constant-fold,
// R5-proven pattern): slot d refilled at step j with u(step j+5),
// consumed at end of step j+4 -> 4 windows (~2400+ cyc) of slack per
// load, 16 loads in flight. Loop should collapse to its compute floor.
// Also: normalize max-reduce restructured 16-deep chain -> 4-level tree.
//
// R10/R11 recap (all verified on HW, absmax 0.0):
//   z[64x16] = E[64x64] * beta[64x16] on the matrix pipe; 16 chains
//   (batches) per wave as columns; 4 row-tiles x 2 K-slabs of
//   mfma_f32_16x16x32_f16; SPLIT-F16 (E=Ehi+Elo, b=bhi+blo,
//   z = Ehi*bhi + Ehi*blo + Elo*bhi -> 24 MFMA/step, err ~2^-21/step).
//   C/D layout (m89): col=lane&15, row=4*(lane>>4)+reg. A/B loaded with
//   the SAME (h,e)->k bijection (k-order cancels). C layout == B layout
//   -> output feeds next step's B fragment with zero cross-lane movement.
//   Per-column max-exponent normalization (uint max on positive floats +
//   shfl_xor 16,32), exact int esum, applied once at the end.
//   Structure: 64 blocks x 128 threads; wave0 fwd chain (255 steps,
//   t=1..255) + gold + meet; wave1 bwd chain (256 steps) -> LDS handoff.
//   score = log(sum_k x_k y_k) + (esumA+esumB)*ln2.

#define BB 1024
#define TT 512
#define KK 64
#define START_TAG 62
#define NBLK 64
#define GB 16

typedef _Float16 f16;
typedef f16   f16x8 __attribute__((ext_vector_type(8)));
typedef float f32x4 __attribute__((ext_vector_type(4)));

union W8 { f16x8 v; f16 e[8]; };

#define MFMA16(A, B, C) __builtin_amdgcn_mfma_f32_16x16x32_f16((A), (B), (C), 0, 0, 0)

__device__ __forceinline__ f32x4 exp4(f32x4 u) {
  f32x4 r; r.x = __expf(u.x); r.y = __expf(u.y); r.z = __expf(u.z); r.w = __expf(u.w);
  return r;
}

__device__ __forceinline__ unsigned umaxu(unsigned a, unsigned b) { return a > b ? a : b; }

// per-column max-exponent normalization: v = q * 2^-e, esum += e (tree max)
__device__ __forceinline__ void normalize(const f32x4 (&q)[4], f32x4 (&v)[4], int& esum) {
  unsigned t0 = umaxu(umaxu(__float_as_uint(q[0].x), __float_as_uint(q[0].y)),
                      umaxu(__float_as_uint(q[0].z), __float_as_uint(q[0].w)));
  unsigned t1 = umaxu(umaxu(__float_as_uint(q[1].x), __float_as_uint(q[1].y)),
                      umaxu(__float_as_uint(q[1].z), __float_as_uint(q[1].w)));
  unsigned t2 = umaxu(umaxu(__float_as_uint(q[2].x), __float_as_uint(q[2].y)),
                      umaxu(__float_as_uint(q[2].z), __float_as_uint(q[2].w)));
  unsigned t3 = umaxu(umaxu(__float_as_uint(q[3].x), __float_as_uint(q[3].y)),
                      umaxu(__float_as_uint(q[3].z), __float_as_uint(q[3].w)));
  unsigned mb = umaxu(umaxu(t0, t1), umaxu(t2, t3));
  mb = umaxu(mb, (unsigned)__shfl_xor((int)mb, 16));
  mb = umaxu(mb, (unsigned)__shfl_xor((int)mb, 32));
  esum += (int)(mb >> 23) - 127;
  const float s = __uint_as_float(0x7F000000u - (mb & 0x7F800000u));
  #pragma unroll
  for (int tau = 0; tau < 4; ++tau) v[tau] = q[tau] * s;
}

// split-f16 pack: element e of slab S = v[2S + (e>>2)][e&3] (matches A k-map)
__device__ __forceinline__ void pack_w(const f32x4 (&v)[4], W8 (&whi)[2], W8 (&wlo)[2]) {
  #pragma unroll
  for (int S = 0; S < 2; ++S) {
    #pragma unroll
    for (int c = 0; c < 2; ++c) {
      const f32x4 t = v[2 * S + c];
      const f16 h0 = (f16)t.x, h1 = (f16)t.y, h2 = (f16)t.z, h3 = (f16)t.w;
      whi[S].e[4 * c + 0] = h0;
      whi[S].e[4 * c + 1] = h1;
      whi[S].e[4 * c + 2] = h2;
      whi[S].e[4 * c + 3] = h3;
      wlo[S].e[4 * c + 0] = (f16)(t.x - (float)h0);
      wlo[S].e[4 * c + 1] = (f16)(t.y - (float)h1);
      wlo[S].e[4 * c + 2] = (f16)(t.z - (float)h2);
      wlo[S].e[4 * c + 3] = (f16)(t.w - (float)h3);
    }
  }
}

// one recurrence step: z = E*w (24 MFMA, split-3)
__device__ __forceinline__ void mfma_step(const W8 (&Ehi)[4][2], const W8 (&Elo)[4][2],
                                          const W8 (&whi)[2], const W8 (&wlo)[2],
                                          f32x4 (&acc)[4]) {
  #pragma unroll
  for (int tau = 0; tau < 4; ++tau) {
    f32x4 a = {0.f, 0.f, 0.f, 0.f};
    a = MFMA16(Ehi[tau][0].v, whi[0].v, a);
    a = MFMA16(Ehi[tau][1].v, whi[1].v, a);
    a = MFMA16(Elo[tau][0].v, whi[0].v, a);
    a = MFMA16(Elo[tau][1].v, whi[1].v, a);
    a = MFMA16(Ehi[tau][0].v, wlo[0].v, a);
    a = MFMA16(Ehi[tau][1].v, wlo[1].v, a);
    acc[tau] = a;
  }
}

// DIR=0: fwd x = prod_{t=1..255}(D_t E) beta0   (255 MFMA-steps)
// DIR=1: bwd y = E^T D_256 ... E^T D_511 1      (256 MFMA-steps)
// g-step j -> t: fwd t = 1+j ; bwd t = 510-j (u_511 consumed at init).
template <int DIR>
__device__ __forceinline__ void run_chain(const float* __restrict__ feats,
                                          const float* __restrict__ trans,
                                          int blk, int lane,
                                          f32x4 (&v)[4], int& esum) {
  const int m = lane & 15;
  const int h = lane >> 4;

  // ---- E fragments, split hi/lo. A k-map: k = 32S + 16(e>>2) + 4h + (e&3)
  W8 Ehi[4][2], Elo[4][2];
  #pragma unroll
  for (int tau = 0; tau < 4; ++tau)
    #pragma unroll
    for (int S = 0; S < 2; ++S)
      #pragma unroll
      for (int e = 0; e < 8; ++e) {
        const int kk = 32 * S + 16 * (e >> 2) + 4 * h + (e & 3);
        const int row = 16 * tau + m;
        const float val = __expf(DIR ? trans[kk * KK + row] : trans[row * KK + kk]);
        const f16 hi = (f16)val;
        Ehi[tau][S].e[e] = hi;
        Elo[tau][S].e[e] = (f16)(val - (float)hi);
      }

  const float* fB = feats + (size_t)(blk * GB + m) * TT * KK + 4 * h;

  // ---- feat ring: slot d holds u(g-step j), d = j%5; 4 windows of slack
  f32x4 uR[5][4];
  #pragma unroll
  for (int d = 0; d < 5; ++d) {
    const int t = DIR ? (510 - d) : (1 + d);
    #pragma unroll
    for (int tau = 0; tau < 4; ++tau)
      uR[d][tau] = *(const f32x4*)(fB + (size_t)t * KK + 16 * tau);
  }

  W8 whi[2], wlo[2];
  f32x4 g[4];
  esum = 0;

  if (DIR == 0) {
    f32x4 vv[4];
    #pragma unroll
    for (int tau = 0; tau < 4; ++tau) vv[tau] = (f32x4){0.f, 0.f, 0.f, 0.f};
    if (h == 3) vv[3].z = 1.0f;   // row 62 = 16*3 + 4*3 + 2
    pack_w(vv, whi, wlo);
  } else {
    f32x4 q[4];
    #pragma unroll
    for (int tau = 0; tau < 4; ++tau)
      q[tau] = exp4(*(const f32x4*)(fB + (size_t)511 * KK + 16 * tau));
    normalize(q, v, esum);          // w0 = pack(exp(u_511)), normalized
    pack_w(v, whi, wlo);
  }
  #pragma unroll
  for (int tau = 0; tau < 4; ++tau) g[tau] = exp4(uR[0][tau]);  // g-step 0

  for (int gg = 0; gg < 51; ++gg) {
    #pragma unroll
    for (int d = 0; d < 5; ++d) {
      const int j = 5 * gg + d;     // g-step 0..254

      f32x4 acc[4];
      mfma_step(Ehi, Elo, whi, wlo, acc);

      // refill slot d with g-step j+5 (clamped; clamped dups are unused)
      int tn = DIR ? (510 - (j + 5)) : (1 + (j + 5));
      if (DIR) { if (tn < 256) tn = 256; } else { if (tn > 255) tn = 255; }
      #pragma unroll
      for (int tau = 0; tau < 4; ++tau)
        uR[d][tau] = *(const f32x4*)(fB + (size_t)tn * KK + 16 * tau);

      f32x4 q[4];
      #pragma unroll
      for (int tau = 0; tau < 4; ++tau) q[tau] = acc[tau] * g[tau];
      normalize(q, v, esum);
      pack_w(v, whi, wlo);

      // g for step j+1: slot loaded at step j-4 (or init) -> 4-window slack
      const int dn = (d + 1 < 5) ? d + 1 : 0;
      #pragma unroll
      for (int tau = 0; tau < 4; ++tau) g[tau] = exp4(uR[dn][tau]);
    }
  }

  if (DIR == 1) {                   // final step t=256: matvec only, no g
    f32x4 acc[4];
    mfma_step(Ehi, Elo, whi, wlo, acc);
    normalize(acc, v, esum);
  }
}

__global__ __launch_bounds__(128, 1) void crf_mfma_kernel(
    const float* __restrict__ feats,   // [B, T, K]
    const int*   __restrict__ tags,    // [B, T]
    const float* __restrict__ trans,   // [K, K]  trans[i*K+j] = score j -> i
    float*       __restrict__ diff)    // [B]  forward - gold
{
  const int lane = threadIdx.x & 63;
  const int wv   = threadIdx.x >> 6;
  const int blk  = blockIdx.x;
  const int m = lane & 15;
  const int h = lane >> 4;

  __shared__ float ysh[KK][GB];
  __shared__ int   esum_sh[GB];

  f32x4 v[4];
  int esum;

  if (wv == 1) {
    run_chain<1>(feats, trans, blk, lane, v, esum);
    #pragma unroll
    for (int tau = 0; tau < 4; ++tau) {
      ysh[16 * tau + 4 * h + 0][m] = v[tau].x;
      ysh[16 * tau + 4 * h + 1][m] = v[tau].y;
      ysh[16 * tau + 4 * h + 2][m] = v[tau].z;
      ysh[16 * tau + 4 * h + 3][m] = v[tau].w;
    }
    if (lane < 16) esum_sh[lane] = esum;
    __syncthreads();
  } else {
    run_chain<0>(feats, trans, blk, lane, v, esum);

    // ---- gold path score: lane (m,h) covers tt = 1+h, stride 4
    const int bglob = blk * GB + m;
    const int* tg = tags + bglob * TT;
    const float* fg = feats + (size_t)bglob * TT * KK;
    float gs = 0.f;
    #pragma unroll 8
    for (int tt = 1 + h; tt < TT; tt += 4) {
      const int tc = tg[tt];
      const int tp = tg[tt - 1];
      gs += trans[tc * KK + tp] + fg[(size_t)tt * KK + tc];
    }
    gs += __shfl_xor(gs, 16);
    gs += __shfl_xor(gs, 32);

    __syncthreads();

    // ---- meet: p_b = sum_k x[k,b] * y[k,b]
    float p = 0.f;
    #pragma unroll
    for (int tau = 0; tau < 4; ++tau) {
      p += v[tau].x * ysh[16 * tau + 4 * h + 0][m];
      p += v[tau].y * ysh[16 * tau + 4 * h + 1][m];
      p += v[tau].z * ysh[16 * tau + 4 * h + 2][m];
      p += v[tau].w * ysh[16 * tau + 4 * h + 3][m];
    }
    p += __shfl_xor(p, 16);
    p += __shfl_xor(p, 32);

    if (lane < 16)
      diff[blk * GB + lane] =
          __logf(p) + (float)(esum + esum_sh[lane]) * 0.6931471805599453f - gs;
  }
}

__global__ __launch_bounds__(1024) void reduce_mean_kernel(
    const float* __restrict__ diff, float* __restrict__ out)
{
  __shared__ float part[16];
  const int tid = threadIdx.x;
  float v = diff[tid];
  #pragma unroll
  for (int off = 32; off; off >>= 1) v += __shfl_xor(v, off);
  if ((tid & 63) == 0) part[tid >> 6] = v;
  __syncthreads();
  if (tid < 16) {
    float s = part[tid];
    #pragma unroll
    for (int off = 8; off; off >>= 1) s += __shfl_xor(s, off);
    if (tid == 0) out[0] = s * (1.0f / 1024.0f);
  }
}

extern "C" void kernel_launch(void* const* d_in, const int* in_sizes, int n_in,
                              void* d_out, int out_size, void* d_ws, size_t ws_size,
                              hipStream_t stream) {
  const float* feats = (const float*)d_in[0];
  const int*   tags  = (const int*)d_in[1];
  const float* trans = (const float*)d_in[2];
  float* out  = (float*)d_out;
  float* diff = (float*)d_ws;   // 1024 floats of scratch

  crf_mfma_kernel<<<dim3(NBLK), dim3(128), 0, stream>>>(feats, tags, trans, diff);
  reduce_mean_kernel<<<dim3(1), dim3(1024), 0, stream>>>(diff, out);
}

// Round 9
// 249.631 us; speedup vs baseline: 1.6964x; 1.1859x over previous
//
#include <hip/hip_runtime.h>

// CRF forward-score + gold-score, MI355X (gfx950).
//
// R13: RANK-1 SEGMENT SPLIT. R12 (157 us) showed the serial chain is the
// bottleneck: per-step floor ~1100-1400 cyc (issue + MFMA pipe + serial
// epilogue) x 256 steps, at 1.4% occupancy. Fix the STRUCTURE: products
// of 64 positive matrices are numerically rank-1 (Perron gap ~0.2/step
// -> contrast 1e-33 over 64 steps, exact to fp32), so with
//   f_s = P_s * u_s (u_1 = e_START, else 1),  g_s = P_s^T * 1,
//   P_s f ~= f_s (g_s^T f)/(1^T f_s)
// the score telescopes into per-junction dot products:
//   score = sum_{j=1..7} log(g_{j+1}^T f_j) - sum_{j=2..7} log(1^T f_j)
//           (+ exact 2^esum bookkeeping) - gold
// One block per (batch-group, junction j): wave0 = f_j (64 fwd steps),
// wave1 = g_{j+1} (64 bwd steps), LDS meet, atomicAdd into diff[b].
// Serial chain 256 -> 64 steps; waves 128 -> 896 (448 blocks).
// Feats read ~1.9x, second reader is a concurrent neighbor block ->
// L2/LLC absorbs (feats 128 MB < 256 MB LLC).
//
// Per-step machinery is byte-identical to the verified R12 (absmax 0.0):
//   z[64x16] = E * w on the matrix pipe, 16 chains/wave as columns,
//   4 row-tiles x 2 K-slabs of mfma_f32_16x16x32_f16, SPLIT-F16
//   (z = Ehi*whi + Elo*whi + Ehi*wlo, 24 MFMA/step, err ~2^-21/step);
//   C/D layout col=lane&15,row=4*(lane>>4)+reg; A/B share the (h,e)->k
//   bijection (k-order cancels); C layout == B layout -> zero cross-lane
//   recurrence; per-column max-exponent normalization + exact int esum;
//   feat register ring (depth 4 here, 64=4x16 so indices constant-fold).

#define BB 1024
#define TT 512
#define KK 64
#define GB 16
#define NJ 7          // junctions (8 segments)
#define SEGLEN 64
#define LN2F 0.6931471805599453f

typedef _Float16 f16;
typedef f16   f16x8 __attribute__((ext_vector_type(8)));
typedef float f32x4 __attribute__((ext_vector_type(4)));

union W8 { f16x8 v; f16 e[8]; };

#define MFMA16(A, B, C) __builtin_amdgcn_mfma_f32_16x16x32_f16((A), (B), (C), 0, 0, 0)

__device__ __forceinline__ f32x4 exp4(f32x4 u) {
  f32x4 r; r.x = __expf(u.x); r.y = __expf(u.y); r.z = __expf(u.z); r.w = __expf(u.w);
  return r;
}

__device__ __forceinline__ unsigned umaxu(unsigned a, unsigned b) { return a > b ? a : b; }

// per-column max-exponent normalization: v = q * 2^-e, esum += e (tree max)
__device__ __forceinline__ void normalize(const f32x4 (&q)[4], f32x4 (&v)[4], int& esum) {
  unsigned t0 = umaxu(umaxu(__float_as_uint(q[0].x), __float_as_uint(q[0].y)),
                      umaxu(__float_as_uint(q[0].z), __float_as_uint(q[0].w)));
  unsigned t1 = umaxu(umaxu(__float_as_uint(q[1].x), __float_as_uint(q[1].y)),
                      umaxu(__float_as_uint(q[1].z), __float_as_uint(q[1].w)));
  unsigned t2 = umaxu(umaxu(__float_as_uint(q[2].x), __float_as_uint(q[2].y)),
                      umaxu(__float_as_uint(q[2].z), __float_as_uint(q[2].w)));
  unsigned t3 = umaxu(umaxu(__float_as_uint(q[3].x), __float_as_uint(q[3].y)),
                      umaxu(__float_as_uint(q[3].z), __float_as_uint(q[3].w)));
  unsigned mb = umaxu(umaxu(t0, t1), umaxu(t2, t3));
  mb = umaxu(mb, (unsigned)__shfl_xor((int)mb, 16));
  mb = umaxu(mb, (unsigned)__shfl_xor((int)mb, 32));
  esum += (int)(mb >> 23) - 127;
  const float s = __uint_as_float(0x7F000000u - (mb & 0x7F800000u));
  #pragma unroll
  for (int tau = 0; tau < 4; ++tau) v[tau] = q[tau] * s;
}

// split-f16 pack: element e of slab S = v[2S + (e>>2)][e&3] (matches A k-map)
__device__ __forceinline__ void pack_w(const f32x4 (&v)[4], W8 (&whi)[2], W8 (&wlo)[2]) {
  #pragma unroll
  for (int S = 0; S < 2; ++S) {
    #pragma unroll
    for (int c = 0; c < 2; ++c) {
      const f32x4 t = v[2 * S + c];
      const f16 h0 = (f16)t.x, h1 = (f16)t.y, h2 = (f16)t.z, h3 = (f16)t.w;
      whi[S].e[4 * c + 0] = h0;
      whi[S].e[4 * c + 1] = h1;
      whi[S].e[4 * c + 2] = h2;
      whi[S].e[4 * c + 3] = h3;
      wlo[S].e[4 * c + 0] = (f16)(t.x - (float)h0);
      wlo[S].e[4 * c + 1] = (f16)(t.y - (float)h1);
      wlo[S].e[4 * c + 2] = (f16)(t.z - (float)h2);
      wlo[S].e[4 * c + 3] = (f16)(t.w - (float)h3);
    }
  }
}

// one recurrence step: z = E*w (24 MFMA, split-3)
__device__ __forceinline__ void mfma_step(const W8 (&Ehi)[4][2], const W8 (&Elo)[4][2],
                                          const W8 (&whi)[2], const W8 (&wlo)[2],
                                          f32x4 (&acc)[4]) {
  #pragma unroll
  for (int tau = 0; tau < 4; ++tau) {
    f32x4 a = {0.f, 0.f, 0.f, 0.f};
    a = MFMA16(Ehi[tau][0].v, whi[0].v, a);
    a = MFMA16(Ehi[tau][1].v, whi[1].v, a);
    a = MFMA16(Elo[tau][0].v, whi[0].v, a);
    a = MFMA16(Elo[tau][1].v, whi[1].v, a);
    a = MFMA16(Ehi[tau][0].v, wlo[0].v, a);
    a = MFMA16(Ehi[tau][1].v, wlo[1].v, a);
    acc[tau] = a;
  }
}

// one chain step with compile-time ring slot D (runtime j only in addresses)
template <int DIR, int D>
__device__ __forceinline__ void step_one(
    const float* __restrict__ fB, int j, int t_lo, int t_hi,
    const W8 (&Ehi)[4][2], const W8 (&Elo)[4][2],
    W8 (&whi)[2], W8 (&wlo)[2],
    f32x4 (&uR)[4][4], f32x4 (&g)[4],
    f32x4 (&v)[4], int& esum)
{
  f32x4 acc[4];
  mfma_step(Ehi, Elo, whi, wlo, acc);

  // refill slot D with this chain's step j+4 (clamped; clamped dups unused)
  int tn = DIR ? (t_hi - 1 - (j + 4)) : (t_lo + (j + 4));
  if (DIR) { if (tn < t_lo) tn = t_lo; } else { if (tn > t_hi) tn = t_hi; }
  #pragma unroll
  for (int tau = 0; tau < 4; ++tau)
    uR[D][tau] = *(const f32x4*)(fB + (size_t)tn * KK + 16 * tau);

  f32x4 q[4];
  #pragma unroll
  for (int tau = 0; tau < 4; ++tau) q[tau] = acc[tau] * g[tau];
  normalize(q, v, esum);
  pack_w(v, whi, wlo);

  constexpr int DN = (D + 1) & 3;
  #pragma unroll
  for (int tau = 0; tau < 4; ++tau) g[tau] = exp4(uR[DN][tau]);
}

// DIR=0: f = prod_{t=t_lo..t_hi ascending}(D_t E) u   (nstep = t_hi-t_lo+1 steps)
// DIR=1: g = E^T D_{t_lo} ... E^T D_{t_hi} 1          (nstep = t_hi-t_lo loop + tail)
template <int DIR>
__device__ __forceinline__ void run_seg(
    const float* __restrict__ feats, const float* __restrict__ trans,
    int grp, int lane, int t_lo, int t_hi, int nstep, int one_hot,
    f32x4 (&v)[4], int& esum)
{
  const int m = lane & 15;
  const int h = lane >> 4;

  // ---- E fragments, split hi/lo. A k-map: k = 32S + 16(e>>2) + 4h + (e&3)
  W8 Ehi[4][2], Elo[4][2];
  #pragma unroll
  for (int tau = 0; tau < 4; ++tau)
    #pragma unroll
    for (int S = 0; S < 2; ++S)
      #pragma unroll
      for (int e = 0; e < 8; ++e) {
        const int kk = 32 * S + 16 * (e >> 2) + 4 * h + (e & 3);
        const int row = 16 * tau + m;
        const float val = __expf(DIR ? trans[kk * KK + row] : trans[row * KK + kk]);
        const f16 hi = (f16)val;
        Ehi[tau][S].e[e] = hi;
        Elo[tau][S].e[e] = (f16)(val - (float)hi);
      }

  const float* fB = feats + (size_t)(grp * GB + m) * TT * KK + 4 * h;

  // ---- feat ring, depth 4 (3 windows of slack)
  f32x4 uR[4][4];
  #pragma unroll
  for (int d = 0; d < 4; ++d) {
    int t = DIR ? (t_hi - 1 - d) : (t_lo + d);
    if (DIR) { if (t < t_lo) t = t_lo; } else { if (t > t_hi) t = t_hi; }
    #pragma unroll
    for (int tau = 0; tau < 4; ++tau)
      uR[d][tau] = *(const f32x4*)(fB + (size_t)t * KK + 16 * tau);
  }

  W8 whi[2], wlo[2];
  f32x4 g[4];
  esum = 0;

  if (DIR == 0) {
    f32x4 vv[4];
    if (one_hot) {
      #pragma unroll
      for (int tau = 0; tau < 4; ++tau) vv[tau] = (f32x4){0.f, 0.f, 0.f, 0.f};
      if (h == 3) vv[3].z = 1.0f;   // row 62 = 16*3 + 4*3 + 2 (START)
    } else {
      #pragma unroll
      for (int tau = 0; tau < 4; ++tau) vv[tau] = (f32x4){1.f, 1.f, 1.f, 1.f};
    }
    pack_w(vv, whi, wlo);
  } else {
    f32x4 q[4];
    #pragma unroll
    for (int tau = 0; tau < 4; ++tau)
      q[tau] = exp4(*(const f32x4*)(fB + (size_t)t_hi * KK + 16 * tau));
    normalize(q, v, esum);          // w0 = pack(exp(u_{t_hi})), normalized
    pack_w(v, whi, wlo);
  }
  #pragma unroll
  for (int tau = 0; tau < 4; ++tau) g[tau] = exp4(uR[0][tau]);

  const int nq = nstep >> 2;
  for (int gg = 0; gg < nq; ++gg) {
    const int j = 4 * gg;
    step_one<DIR, 0>(fB, j + 0, t_lo, t_hi, Ehi, Elo, whi, wlo, uR, g, v, esum);
    step_one<DIR, 1>(fB, j + 1, t_lo, t_hi, Ehi, Elo, whi, wlo, uR, g, v, esum);
    step_one<DIR, 2>(fB, j + 2, t_lo, t_hi, Ehi, Elo, whi, wlo, uR, g, v, esum);
    step_one<DIR, 3>(fB, j + 3, t_lo, t_hi, Ehi, Elo, whi, wlo, uR, g, v, esum);
  }
  const int jr = 4 * nq;
  const int rem = nstep & 3;
  if (rem > 0) step_one<DIR, 0>(fB, jr + 0, t_lo, t_hi, Ehi, Elo, whi, wlo, uR, g, v, esum);
  if (rem > 1) step_one<DIR, 1>(fB, jr + 1, t_lo, t_hi, Ehi, Elo, whi, wlo, uR, g, v, esum);
  if (rem > 2) step_one<DIR, 2>(fB, jr + 2, t_lo, t_hi, Ehi, Elo, whi, wlo, uR, g, v, esum);

  if (DIR == 1) {                   // tail: final E^T, no D
    f32x4 acc[4];
    mfma_step(Ehi, Elo, whi, wlo, acc);
    normalize(acc, v, esum);
  }
}

__global__ void zero_diff_kernel(float* __restrict__ diff) {
  diff[threadIdx.x] = 0.0f;
}

__global__ __launch_bounds__(128, 1) void crf_seg_kernel(
    const float* __restrict__ feats,   // [B, T, K]
    const int*   __restrict__ tags,    // [B, T]
    const float* __restrict__ trans,   // [K, K]  trans[i*K+j] = score j -> i
    float*       __restrict__ diff)    // [B]  forward - gold (accumulated)
{
  const int lane = threadIdx.x & 63;
  const int wv   = threadIdx.x >> 6;
  const int grp  = blockIdx.x / NJ;        // 0..63 (16 batches each)
  const int j    = 1 + blockIdx.x % NJ;    // junction 1..7
  const int m = lane & 15;
  const int h = lane >> 4;

  __shared__ float ysh[KK][GB];
  __shared__ int   esum_sh[GB];

  f32x4 v[4];
  int esum;

  if (wv == 1) {
    // g_{j+1}: bwd over segment j+1 = [64j+1 .. min(64(j+1), 511)]
    const int t_lo = SEGLEN * j + 1;
    const int t_hi = (j == NJ) ? (TT - 1) : SEGLEN * (j + 1);
    run_seg<1>(feats, trans, grp, lane, t_lo, t_hi, t_hi - t_lo, 0, v, esum);
    #pragma unroll
    for (int tau = 0; tau < 4; ++tau) {
      ysh[16 * tau + 4 * h + 0][m] = v[tau].x;
      ysh[16 * tau + 4 * h + 1][m] = v[tau].y;
      ysh[16 * tau + 4 * h + 2][m] = v[tau].z;
      ysh[16 * tau + 4 * h + 3][m] = v[tau].w;
    }
    if (lane < 16) esum_sh[lane] = esum;
    __syncthreads();
  } else {
    // f_j: fwd over segment j = [64(j-1)+1 .. 64j]; one-hot start iff j==1
    const int t_lo = SEGLEN * (j - 1) + 1;
    const int t_hi = SEGLEN * j;
    run_seg<0>(feats, trans, grp, lane, t_lo, t_hi, SEGLEN, j == 1, v, esum);

    // ---- gold path score (junction 1 only): lane (m,h) covers tt=1+h, +4
    float gs = 0.f;
    if (j == 1) {
      const int bglob = grp * GB + m;
      const int* tg = tags + bglob * TT;
      const float* fg = feats + (size_t)bglob * TT * KK;
      #pragma unroll 8
      for (int tt = 1 + h; tt < TT; tt += 4) {
        const int tc = tg[tt];
        const int tp = tg[tt - 1];
        gs += trans[tc * KK + tp] + fg[(size_t)tt * KK + tc];
      }
      gs += __shfl_xor(gs, 16);
      gs += __shfl_xor(gs, 32);
    }

    __syncthreads();

    // ---- junction dots: A = g~^T f~ ; Bs = 1^T f~  (per column m)
    float A = 0.f, Bs = 0.f;
    #pragma unroll
    for (int tau = 0; tau < 4; ++tau) {
      A += v[tau].x * ysh[16 * tau + 4 * h + 0][m];
      A += v[tau].y * ysh[16 * tau + 4 * h + 1][m];
      A += v[tau].z * ysh[16 * tau + 4 * h + 2][m];
      A += v[tau].w * ysh[16 * tau + 4 * h + 3][m];
      Bs += (v[tau].x + v[tau].y) + (v[tau].z + v[tau].w);
    }
    A  += __shfl_xor(A, 16);  A  += __shfl_xor(A, 32);
    Bs += __shfl_xor(Bs, 16); Bs += __shfl_xor(Bs, 32);

    if (lane < 16) {
      // c_j = log(A) + (ef+eg)ln2 - [j>1](log(Bs) + ef*ln2) - [j==1] gold
      float c = __logf(A) + (float)(esum + esum_sh[lane]) * LN2F - gs;
      if (j > 1) c -= __logf(Bs) + (float)esum * LN2F;
      atomicAdd(&diff[grp * GB + lane], c);
    }
  }
}

__global__ __launch_bounds__(1024) void reduce_mean_kernel(
    const float* __restrict__ diff, float* __restrict__ out)
{
  __shared__ float part[16];
  const int tid = threadIdx.x;
  float v = diff[tid];
  #pragma unroll
  for (int off = 32; off; off >>= 1) v += __shfl_xor(v, off);
  if ((tid & 63) == 0) part[tid >> 6] = v;
  __syncthreads();
  if (tid < 16) {
    float s = part[tid];
    #pragma unroll
    for (int off = 8; off; off >>= 1) s += __shfl_xor(s, off);
    if (tid == 0) out[0] = s * (1.0f / 1024.0f);
  }
}

extern "C" void kernel_launch(void* const* d_in, const int* in_sizes, int n_in,
                              void* d_out, int out_size, void* d_ws, size_t ws_size,
                              hipStream_t stream) {
  const float* feats = (const float*)d_in[0];
  const int*   tags  = (const int*)d_in[1];
  const float* trans = (const float*)d_in[2];
  float* out  = (float*)d_out;
  float* diff = (float*)d_ws;   // 1024 floats of scratch

  zero_diff_kernel<<<dim3(1), dim3(1024), 0, stream>>>(diff);
  crf_seg_kernel<<<dim3(64 * NJ), dim3(128), 0, stream>>>(feats, tags, trans, diff);
  reduce_mean_kernel<<<dim3(1), dim3(1024), 0, stream>>>(diff, out);
}

// Round 10
// 228.287 us; speedup vs baseline: 1.8550x; 1.0935x over previous
//
#include <hip/hip_runtime.h>

// CRF forward-score + gold-score, MI355X (gfx950).
//
// R14 = R13 with the two free parameters scaled (machinery untouched):
//  1. SEGLEN 64->32, NJ 7->15: rank-1 contrast (l2/l1)^32 <= ~1e-10,
//     still exact to fp32. Serial chain 64 -> 32 steps; chain waves
//     896 -> 1920.
//  2. Gold score moved out of j==1 chain blocks into 64 dedicated
//     blocks (uniform chain blocks, no stragglers). Grid = 960 chain
//     + 64 gold = 1024 blocks = 2048 waves = exactly 2 waves/SIMD,
//     all co-resident (VGPR 120 < 128) -> two independent chains
//     interleave per SIMD and hide the exposed dependent-chain latency
//     R13 measured (~4000 cyc/step at 0.875 waves/SIMD; MFMA pipe only
//     360, VALU issue 670 -> ~3000 cyc was uncovered latency).
//
// R13 (verified absmax 0.0): rank-1 segment split. Products of SEGLEN
// positive matrices are numerically rank-1, so with
//   f_s = P_s u_s (u_1 = e_START else 1),  g_s = P_s^T 1,
//   P_s f ~= f_s (g_s^T f)/(1^T f_s)
// score telescopes into junction dots:
//   score = sum_{j=1..NJ} log(g_{j+1}^T f_j) - sum_{j=2..NJ} log(1^T f_j)
//           (+ exact 2^esum bookkeeping) - gold
// Block (grp, j): wave0 = f_j (fwd), wave1 = g_{j+1} (bwd), LDS meet,
// atomicAdd into diff[b]. Feats read ~2x but die-level LLC (256 MB >
// 128 MB feats) dedups the second reader (R13: FETCH 148 MB at 1.16x).
//
// Per-step machinery (verified R11/R12/R13, absmax 0.0): z[64x16] = E*w
// on the matrix pipe, 16 chains/wave as columns, 4 row-tiles x 2 K-slabs
// of mfma_f32_16x16x32_f16, SPLIT-F16 (z = Ehi*whi + Elo*whi + Ehi*wlo,
// 24 MFMA/step, err ~2^-21/step); C/D layout col=lane&15,
// row=4*(lane>>4)+reg; A/B share the (h,e)->k bijection; C layout == B
// layout -> zero cross-lane recurrence; per-column max-exponent
// normalization + exact int esum; feat register ring depth 4.

#define BB 1024
#define TT 512
#define KK 64
#define GB 16
#define NJ 15         // junctions (16 segments)
#define SEGLEN 32
#define LN2F 0.6931471805599453f

typedef _Float16 f16;
typedef f16   f16x8 __attribute__((ext_vector_type(8)));
typedef float f32x4 __attribute__((ext_vector_type(4)));

union W8 { f16x8 v; f16 e[8]; };

#define MFMA16(A, B, C) __builtin_amdgcn_mfma_f32_16x16x32_f16((A), (B), (C), 0, 0, 0)

__device__ __forceinline__ f32x4 exp4(f32x4 u) {
  f32x4 r; r.x = __expf(u.x); r.y = __expf(u.y); r.z = __expf(u.z); r.w = __expf(u.w);
  return r;
}

__device__ __forceinline__ unsigned umaxu(unsigned a, unsigned b) { return a > b ? a : b; }

// per-column max-exponent normalization: v = q * 2^-e, esum += e (tree max)
__device__ __forceinline__ void normalize(const f32x4 (&q)[4], f32x4 (&v)[4], int& esum) {
  unsigned t0 = umaxu(umaxu(__float_as_uint(q[0].x), __float_as_uint(q[0].y)),
                      umaxu(__float_as_uint(q[0].z), __float_as_uint(q[0].w)));
  unsigned t1 = umaxu(umaxu(__float_as_uint(q[1].x), __float_as_uint(q[1].y)),
                      umaxu(__float_as_uint(q[1].z), __float_as_uint(q[1].w)));
  unsigned t2 = umaxu(umaxu(__float_as_uint(q[2].x), __float_as_uint(q[2].y)),
                      umaxu(__float_as_uint(q[2].z), __float_as_uint(q[2].w)));
  unsigned t3 = umaxu(umaxu(__float_as_uint(q[3].x), __float_as_uint(q[3].y)),
                      umaxu(__float_as_uint(q[3].z), __float_as_uint(q[3].w)));
  unsigned mb = umaxu(umaxu(t0, t1), umaxu(t2, t3));
  mb = umaxu(mb, (unsigned)__shfl_xor((int)mb, 16));
  mb = umaxu(mb, (unsigned)__shfl_xor((int)mb, 32));
  esum += (int)(mb >> 23) - 127;
  const float s = __uint_as_float(0x7F000000u - (mb & 0x7F800000u));
  #pragma unroll
  for (int tau = 0; tau < 4; ++tau) v[tau] = q[tau] * s;
}

// split-f16 pack: element e of slab S = v[2S + (e>>2)][e&3] (matches A k-map)
__device__ __forceinline__ void pack_w(const f32x4 (&v)[4], W8 (&whi)[2], W8 (&wlo)[2]) {
  #pragma unroll
  for (int S = 0; S < 2; ++S) {
    #pragma unroll
    for (int c = 0; c < 2; ++c) {
      const f32x4 t = v[2 * S + c];
      const f16 h0 = (f16)t.x, h1 = (f16)t.y, h2 = (f16)t.z, h3 = (f16)t.w;
      whi[S].e[4 * c + 0] = h0;
      whi[S].e[4 * c + 1] = h1;
      whi[S].e[4 * c + 2] = h2;
      whi[S].e[4 * c + 3] = h3;
      wlo[S].e[4 * c + 0] = (f16)(t.x - (float)h0);
      wlo[S].e[4 * c + 1] = (f16)(t.y - (float)h1);
      wlo[S].e[4 * c + 2] = (f16)(t.z - (float)h2);
      wlo[S].e[4 * c + 3] = (f16)(t.w - (float)h3);
    }
  }
}

// one recurrence step: z = E*w (24 MFMA, split-3)
__device__ __forceinline__ void mfma_step(const W8 (&Ehi)[4][2], const W8 (&Elo)[4][2],
                                          const W8 (&whi)[2], const W8 (&wlo)[2],
                                          f32x4 (&acc)[4]) {
  #pragma unroll
  for (int tau = 0; tau < 4; ++tau) {
    f32x4 a = {0.f, 0.f, 0.f, 0.f};
    a = MFMA16(Ehi[tau][0].v, whi[0].v, a);
    a = MFMA16(Ehi[tau][1].v, whi[1].v, a);
    a = MFMA16(Elo[tau][0].v, whi[0].v, a);
    a = MFMA16(Elo[tau][1].v, whi[1].v, a);
    a = MFMA16(Ehi[tau][0].v, wlo[0].v, a);
    a = MFMA16(Ehi[tau][1].v, wlo[1].v, a);
    acc[tau] = a;
  }
}

// one chain step with compile-time ring slot D (runtime j only in addresses)
template <int DIR, int D>
__device__ __forceinline__ void step_one(
    const float* __restrict__ fB, int j, int t_lo, int t_hi,
    const W8 (&Ehi)[4][2], const W8 (&Elo)[4][2],
    W8 (&whi)[2], W8 (&wlo)[2],
    f32x4 (&uR)[4][4], f32x4 (&g)[4],
    f32x4 (&v)[4], int& esum)
{
  f32x4 acc[4];
  mfma_step(Ehi, Elo, whi, wlo, acc);

  // refill slot D with this chain's step j+4 (clamped; clamped dups unused)
  int tn = DIR ? (t_hi - 1 - (j + 4)) : (t_lo + (j + 4));
  if (DIR) { if (tn < t_lo) tn = t_lo; } else { if (tn > t_hi) tn = t_hi; }
  #pragma unroll
  for (int tau = 0; tau < 4; ++tau)
    uR[D][tau] = *(const f32x4*)(fB + (size_t)tn * KK + 16 * tau);

  f32x4 q[4];
  #pragma unroll
  for (int tau = 0; tau < 4; ++tau) q[tau] = acc[tau] * g[tau];
  normalize(q, v, esum);
  pack_w(v, whi, wlo);

  constexpr int DN = (D + 1) & 3;
  #pragma unroll
  for (int tau = 0; tau < 4; ++tau) g[tau] = exp4(uR[DN][tau]);
}

// DIR=0: f = prod_{t=t_lo..t_hi ascending}(D_t E) u   (nstep = t_hi-t_lo+1 steps)
// DIR=1: g = E^T D_{t_lo} ... E^T D_{t_hi} 1          (nstep = t_hi-t_lo loop + tail)
template <int DIR>
__device__ __forceinline__ void run_seg(
    const float* __restrict__ feats, const float* __restrict__ trans,
    int grp, int lane, int t_lo, int t_hi, int nstep, int one_hot,
    f32x4 (&v)[4], int& esum)
{
  const int m = lane & 15;
  const int h = lane >> 4;

  // ---- E fragments, split hi/lo. A k-map: k = 32S + 16(e>>2) + 4h + (e&3)
  W8 Ehi[4][2], Elo[4][2];
  #pragma unroll
  for (int tau = 0; tau < 4; ++tau)
    #pragma unroll
    for (int S = 0; S < 2; ++S)
      #pragma unroll
      for (int e = 0; e < 8; ++e) {
        const int kk = 32 * S + 16 * (e >> 2) + 4 * h + (e & 3);
        const int row = 16 * tau + m;
        const float val = __expf(DIR ? trans[kk * KK + row] : trans[row * KK + kk]);
        const f16 hi = (f16)val;
        Ehi[tau][S].e[e] = hi;
        Elo[tau][S].e[e] = (f16)(val - (float)hi);
      }

  const float* fB = feats + (size_t)(grp * GB + m) * TT * KK + 4 * h;

  // ---- feat ring, depth 4 (3 windows of slack)
  f32x4 uR[4][4];
  #pragma unroll
  for (int d = 0; d < 4; ++d) {
    int t = DIR ? (t_hi - 1 - d) : (t_lo + d);
    if (DIR) { if (t < t_lo) t = t_lo; } else { if (t > t_hi) t = t_hi; }
    #pragma unroll
    for (int tau = 0; tau < 4; ++tau)
      uR[d][tau] = *(const f32x4*)(fB + (size_t)t * KK + 16 * tau);
  }

  W8 whi[2], wlo[2];
  f32x4 g[4];
  esum = 0;

  if (DIR == 0) {
    f32x4 vv[4];
    if (one_hot) {
      #pragma unroll
      for (int tau = 0; tau < 4; ++tau) vv[tau] = (f32x4){0.f, 0.f, 0.f, 0.f};
      if (h == 3) vv[3].z = 1.0f;   // row 62 = 16*3 + 4*3 + 2 (START)
    } else {
      #pragma unroll
      for (int tau = 0; tau < 4; ++tau) vv[tau] = (f32x4){1.f, 1.f, 1.f, 1.f};
    }
    pack_w(vv, whi, wlo);
  } else {
    f32x4 q[4];
    #pragma unroll
    for (int tau = 0; tau < 4; ++tau)
      q[tau] = exp4(*(const f32x4*)(fB + (size_t)t_hi * KK + 16 * tau));
    normalize(q, v, esum);          // w0 = pack(exp(u_{t_hi})), normalized
    pack_w(v, whi, wlo);
  }
  #pragma unroll
  for (int tau = 0; tau < 4; ++tau) g[tau] = exp4(uR[0][tau]);

  const int nq = nstep >> 2;
  for (int gg = 0; gg < nq; ++gg) {
    const int j = 4 * gg;
    step_one<DIR, 0>(fB, j + 0, t_lo, t_hi, Ehi, Elo, whi, wlo, uR, g, v, esum);
    step_one<DIR, 1>(fB, j + 1, t_lo, t_hi, Ehi, Elo, whi, wlo, uR, g, v, esum);
    step_one<DIR, 2>(fB, j + 2, t_lo, t_hi, Ehi, Elo, whi, wlo, uR, g, v, esum);
    step_one<DIR, 3>(fB, j + 3, t_lo, t_hi, Ehi, Elo, whi, wlo, uR, g, v, esum);
  }
  const int jr = 4 * nq;
  const int rem = nstep & 3;
  if (rem > 0) step_one<DIR, 0>(fB, jr + 0, t_lo, t_hi, Ehi, Elo, whi, wlo, uR, g, v, esum);
  if (rem > 1) step_one<DIR, 1>(fB, jr + 1, t_lo, t_hi, Ehi, Elo, whi, wlo, uR, g, v, esum);
  if (rem > 2) step_one<DIR, 2>(fB, jr + 2, t_lo, t_hi, Ehi, Elo, whi, wlo, uR, g, v, esum);

  if (DIR == 1) {                   // tail: final E^T, no D
    f32x4 acc[4];
    mfma_step(Ehi, Elo, whi, wlo, acc);
    normalize(acc, v, esum);
  }
}

__global__ void zero_diff_kernel(float* __restrict__ diff) {
  diff[threadIdx.x] = 0.0f;
}

__global__ __launch_bounds__(128, 1) void crf_seg_kernel(
    const float* __restrict__ feats,   // [B, T, K]
    const int*   __restrict__ tags,    // [B, T]
    const float* __restrict__ trans,   // [K, K]  trans[i*K+j] = score j -> i
    float*       __restrict__ diff)    // [B]  forward - gold (accumulated)
{
  __shared__ float ysh[KK][GB];
  __shared__ int   esum_sh[GB];
  __shared__ float gpart[GB];

  const int chainBlocks = 64 * NJ;

  if ((int)blockIdx.x < chainBlocks) {
    // ================= chain block (grp, junction j) =================
    const int lane = threadIdx.x & 63;
    const int wv   = threadIdx.x >> 6;
    const int grp  = blockIdx.x / NJ;        // 0..63 (16 batches each)
    const int j    = 1 + blockIdx.x % NJ;    // junction 1..NJ
    const int m = lane & 15;
    const int h = lane >> 4;

    f32x4 v[4];
    int esum;

    if (wv == 1) {
      // g_{j+1}: bwd over segment j+1 = [SEGLEN*j+1 .. min(SEGLEN*(j+1), 511)]
      const int t_lo = SEGLEN * j + 1;
      const int t_hi = (j == NJ) ? (TT - 1) : SEGLEN * (j + 1);
      run_seg<1>(feats, trans, grp, lane, t_lo, t_hi, t_hi - t_lo, 0, v, esum);
      #pragma unroll
      for (int tau = 0; tau < 4; ++tau) {
        ysh[16 * tau + 4 * h + 0][m] = v[tau].x;
        ysh[16 * tau + 4 * h + 1][m] = v[tau].y;
        ysh[16 * tau + 4 * h + 2][m] = v[tau].z;
        ysh[16 * tau + 4 * h + 3][m] = v[tau].w;
      }
      if (lane < 16) esum_sh[lane] = esum;
      __syncthreads();
    } else {
      // f_j: fwd over segment j; one-hot start iff j==1
      const int t_lo = SEGLEN * (j - 1) + 1;
      const int t_hi = SEGLEN * j;
      run_seg<0>(feats, trans, grp, lane, t_lo, t_hi, SEGLEN, j == 1, v, esum);

      __syncthreads();

      // ---- junction dots: A = g~^T f~ ; Bs = 1^T f~  (per column m)
      float A = 0.f, Bs = 0.f;
      #pragma unroll
      for (int tau = 0; tau < 4; ++tau) {
        A += v[tau].x * ysh[16 * tau + 4 * h + 0][m];
        A += v[tau].y * ysh[16 * tau + 4 * h + 1][m];
        A += v[tau].z * ysh[16 * tau + 4 * h + 2][m];
        A += v[tau].w * ysh[16 * tau + 4 * h + 3][m];
        Bs += (v[tau].x + v[tau].y) + (v[tau].z + v[tau].w);
      }
      A  += __shfl_xor(A, 16);  A  += __shfl_xor(A, 32);
      Bs += __shfl_xor(Bs, 16); Bs += __shfl_xor(Bs, 32);

      if (lane < 16) {
        // c_j = log(A) + (ef+eg)ln2 - [j>1](log(Bs) + ef*ln2)
        float c = __logf(A) + (float)(esum + esum_sh[lane]) * LN2F;
        if (j > 1) c -= __logf(Bs) + (float)esum * LN2F;
        atomicAdd(&diff[grp * GB + lane], c);
      }
    }
  } else {
    // ================= gold block (one per batch-group) =================
    const int grp = blockIdx.x - chainBlocks;
    const int tid = threadIdx.x;
    const int m   = tid & 15;
    const int h8  = tid >> 4;                // 0..7 across both waves
    const int bglob = grp * GB + m;
    const int* tg = tags + bglob * TT;
    const float* fg = feats + (size_t)bglob * TT * KK;

    float gs = 0.f;
    #pragma unroll 8
    for (int tt = 1 + h8; tt < TT; tt += 8) {
      const int tc = tg[tt];
      const int tp = tg[tt - 1];
      gs += trans[tc * KK + tp] + fg[(size_t)tt * KK + tc];
    }
    gs += __shfl_xor(gs, 16);
    gs += __shfl_xor(gs, 32);
    // lanes<16 of each wave hold the per-m sum over its 4 h8 values
    if (tid >= 64 && (tid & 63) < 16) gpart[tid & 15] = gs;
    __syncthreads();
    if (tid < 16) atomicAdd(&diff[grp * GB + tid], -(gs + gpart[tid]));
  }
}

__global__ __launch_bounds__(1024) void reduce_mean_kernel(
    const float* __restrict__ diff, float* __restrict__ out)
{
  __shared__ float part[16];
  const int tid = threadIdx.x;
  float v = diff[tid];
  #pragma unroll
  for (int off = 32; off; off >>= 1) v += __shfl_xor(v, off);
  if ((tid & 63) == 0) part[tid >> 6] = v;
  __syncthreads();
  if (tid < 16) {
    float s = part[tid];
    #pragma unroll
    for (int off = 8; off; off >>= 1) s += __shfl_xor(s, off);
    if (tid == 0) out[0] = s * (1.0f / 1024.0f);
  }
}

extern "C" void kernel_launch(void* const* d_in, const int* in_sizes, int n_in,
                              void* d_out, int out_size, void* d_ws, size_t ws_size,
                              hipStream_t stream) {
  const float* feats = (const float*)d_in[0];
  const int*   tags  = (const int*)d_in[1];
  const float* trans = (const float*)d_in[2];
  float* out  = (float*)d_out;
  float* diff = (float*)d_ws;   // 1024 floats of scratch

  zero_diff_kernel<<<dim3(1), dim3(1024), 0, stream>>>(diff);
  crf_seg_kernel<<<dim3(64 * NJ + 64), dim3(128), 0, stream>>>(feats, tags, trans, diff);
  reduce_mean_kernel<<<dim3(1), dim3(1024), 0, stream>>>(diff, out);
}

// Round 11
// 228.013 us; speedup vs baseline: 1.8572x; 1.0012x over previous
//
#include <hip/hip_runtime.h>

// CRF forward-score + gold-score, MI355X (gfx950).
//
// R15 = R14 + critical-path surgery (structure/algebra untouched):
//  1. STALE-BY-ONE NORMALIZER: scale step t's output by 2^-(M_{t-1}+7),
//     M_{t-1} = exact exponent of the PREVIOUS step's column max,
//     computed off-path (in the MFMA shadow). 7 ~ log2(E rowsum ~105).
//     Bound: exp(q) in [-11.5,+7.5] -> f16-safe; M re-measured from real
//     values each step -> no compounding (unlike R2's recursive stale
//     normalizer). esum += M+7 stays exact-int; junction algebra same.
//  2. MFMA accumulation split 6-deep -> 3 x 2-deep chains + 2 adds.
//  Per-step serial path: MFMA(2) -> add -> mul -> pack -> MFMA
//  (~250 cyc vs ~900); tree-max + 2 shfl_xor + exp4 + ring refill all
//  overlap with MFMA. R14 counters showed: VALU issue 650 c/step, MFMA
//  pipe 355 c/step, window 6400 -> latency-bound on the serial chain.
//
// R13/R14 (verified absmax 0.0): rank-1 segment split, SEGLEN=32, NJ=15.
//   f_s = P_s u_s (u_1 = e_START else 1),  g_s = P_s^T 1,
//   score = sum_j log(g_{j+1}^T f_j) - sum_{j>=2} log(1^T f_j)
//           (+ exact 2^esum bookkeeping) - gold
// Block (grp,j): wave0 = f_j fwd, wave1 = g_{j+1} bwd, LDS meet,
// atomicAdd diff[b]. 960 chain + 64 gold blocks = 2048 waves.
//
// Per-step machinery (verified R11-R14): z[64x16] = E*w on matrix pipe,
// 16 chains/wave as columns, 4 row-tiles x 2 K-slabs mfma_f32_16x16x32_f16,
// SPLIT-F16 (z = Ehi*whi + Elo*whi + Ehi*wlo, 24 MFMA/step, ~2^-21/step);
// C/D layout col=lane&15,row=4*(lane>>4)+reg; A/B share (h,e)->k map;
// C layout == B layout -> zero cross-lane recurrence; feat ring depth 4.

#define BB 1024
#define TT 512
#define KK 64
#define GB 16
#define NJ 15         // junctions (16 segments)
#define SEGLEN 32
#define LN2F 0.6931471805599453f

typedef _Float16 f16;
typedef f16   f16x8 __attribute__((ext_vector_type(8)));
typedef float f32x4 __attribute__((ext_vector_type(4)));

union W8 { f16x8 v; f16 e[8]; };

#define MFMA16(A, B, C) __builtin_amdgcn_mfma_f32_16x16x32_f16((A), (B), (C), 0, 0, 0)

__device__ __forceinline__ f32x4 exp4(f32x4 u) {
  f32x4 r; r.x = __expf(u.x); r.y = __expf(u.y); r.z = __expf(u.z); r.w = __expf(u.w);
  return r;
}

__device__ __forceinline__ unsigned umaxu(unsigned a, unsigned b) { return a > b ? a : b; }

// exact exponent of column max (positive floats; bits compare like values)
__device__ __forceinline__ int colmax_exp(const f32x4 (&q)[4]) {
  unsigned t0 = umaxu(umaxu(__float_as_uint(q[0].x), __float_as_uint(q[0].y)),
                      umaxu(__float_as_uint(q[0].z), __float_as_uint(q[0].w)));
  unsigned t1 = umaxu(umaxu(__float_as_uint(q[1].x), __float_as_uint(q[1].y)),
                      umaxu(__float_as_uint(q[1].z), __float_as_uint(q[1].w)));
  unsigned t2 = umaxu(umaxu(__float_as_uint(q[2].x), __float_as_uint(q[2].y)),
                      umaxu(__float_as_uint(q[2].z), __float_as_uint(q[2].w)));
  unsigned t3 = umaxu(umaxu(__float_as_uint(q[3].x), __float_as_uint(q[3].y)),
                      umaxu(__float_as_uint(q[3].z), __float_as_uint(q[3].w)));
  unsigned mb = umaxu(umaxu(t0, t1), umaxu(t2, t3));
  mb = umaxu(mb, (unsigned)__shfl_xor((int)mb, 16));
  mb = umaxu(mb, (unsigned)__shfl_xor((int)mb, 32));
  return (int)(mb >> 23) - 127;
}

// fresh normalization (init only): v = q * 2^-e, esum += e
__device__ __forceinline__ void normalize(const f32x4 (&q)[4], f32x4 (&v)[4], int& esum) {
  const int e = colmax_exp(q);
  esum += e;
  const float s = __uint_as_float((unsigned)(127 - e) << 23);
  #pragma unroll
  for (int tau = 0; tau < 4; ++tau) v[tau] = q[tau] * s;
}

// split-f16 pack: element e of slab S = v[2S + (e>>2)][e&3] (matches A k-map)
__device__ __forceinline__ void pack_w(const f32x4 (&v)[4], W8 (&whi)[2], W8 (&wlo)[2]) {
  #pragma unroll
  for (int S = 0; S < 2; ++S) {
    #pragma unroll
    for (int c = 0; c < 2; ++c) {
      const f32x4 t = v[2 * S + c];
      const f16 h0 = (f16)t.x, h1 = (f16)t.y, h2 = (f16)t.z, h3 = (f16)t.w;
      whi[S].e[4 * c + 0] = h0;
      whi[S].e[4 * c + 1] = h1;
      whi[S].e[4 * c + 2] = h2;
      whi[S].e[4 * c + 3] = h3;
      wlo[S].e[4 * c + 0] = (f16)(t.x - (float)h0);
      wlo[S].e[4 * c + 1] = (f16)(t.y - (float)h1);
      wlo[S].e[4 * c + 2] = (f16)(t.z - (float)h2);
      wlo[S].e[4 * c + 3] = (f16)(t.w - (float)h3);
    }
  }
}

// z = E*w, 24 MFMA as 3 independent 2-deep chains per tau, then 2 adds
__device__ __forceinline__ void mfma_step(const W8 (&Ehi)[4][2], const W8 (&Elo)[4][2],
                                          const W8 (&whi)[2], const W8 (&wlo)[2],
                                          f32x4 (&acc)[4]) {
  #pragma unroll
  for (int tau = 0; tau < 4; ++tau) {
    f32x4 aA = {0.f, 0.f, 0.f, 0.f};
    f32x4 aB = {0.f, 0.f, 0.f, 0.f};
    f32x4 aC = {0.f, 0.f, 0.f, 0.f};
    aA = MFMA16(Ehi[tau][0].v, whi[0].v, aA);
    aB = MFMA16(Elo[tau][0].v, whi[0].v, aB);
    aC = MFMA16(Ehi[tau][0].v, wlo[0].v, aC);
    aA = MFMA16(Ehi[tau][1].v, whi[1].v, aA);
    aB = MFMA16(Elo[tau][1].v, whi[1].v, aB);
    aC = MFMA16(Ehi[tau][1].v, wlo[1].v, aC);
    acc[tau] = (aA + aB) + aC;
  }
}

// one chain step; q holds w_t (f32) on entry, w_{t+1} on exit.
// Scale applied: 2^-(M+7), M = exponent of max(w_t) -- measured here,
// concurrent with the MFMA (off the serial path). esum += M+7 (exact).
template <int DIR, int D>
__device__ __forceinline__ void step_one(
    const float* __restrict__ fB, int j, int t_lo, int t_hi,
    const W8 (&Ehi)[4][2], const W8 (&Elo)[4][2],
    W8 (&whi)[2], W8 (&wlo)[2],
    f32x4 (&uR)[4][4], f32x4 (&g)[4],
    f32x4 (&q)[4], int& esum, bool use_g)
{
  f32x4 acc[4];
  mfma_step(Ehi, Elo, whi, wlo, acc);

  // ---- off-path (MFMA shadow): stale exponent, scale, ring refill
  const int M = colmax_exp(q);
  esum += M + 7;
  const float s = __uint_as_float((unsigned)(120 - M) << 23);  // 2^-(M+7)

  int tn = DIR ? (t_hi - 1 - (j + 4)) : (t_lo + (j + 4));
  if (DIR) { if (tn < t_lo) tn = t_lo; } else { if (tn > t_hi) tn = t_hi; }
  #pragma unroll
  for (int tau = 0; tau < 4; ++tau)
    uR[D][tau] = *(const f32x4*)(fB + (size_t)tn * KK + 16 * tau);

  f32x4 gs[4];
  #pragma unroll
  for (int tau = 0; tau < 4; ++tau)
    gs[tau] = use_g ? (g[tau] * s) : (f32x4){s, s, s, s};

  // ---- serial path: acc -> mul -> pack
  #pragma unroll
  for (int tau = 0; tau < 4; ++tau) q[tau] = acc[tau] * gs[tau];
  pack_w(q, whi, wlo);

  constexpr int DN = (D + 1) & 3;
  #pragma unroll
  for (int tau = 0; tau < 4; ++tau) g[tau] = exp4(uR[DN][tau]);
}

// DIR=0: f = prod_{t=t_lo..t_hi}(D_t E) u      (nstep steps)
// DIR=1: g = E^T D_{t_lo} ... E^T D_{t_hi} 1   (nstep loop + tail)
template <int DIR>
__device__ __forceinline__ void run_seg(
    const float* __restrict__ feats, const float* __restrict__ trans,
    int grp, int lane, int t_lo, int t_hi, int nstep, int one_hot,
    f32x4 (&q)[4], int& esum)
{
  const int m = lane & 15;
  const int h = lane >> 4;

  // ---- E fragments, split hi/lo. A k-map: k = 32S + 16(e>>2) + 4h + (e&3)
  W8 Ehi[4][2], Elo[4][2];
  #pragma unroll
  for (int tau = 0; tau < 4; ++tau)
    #pragma unroll
    for (int S = 0; S < 2; ++S)
      #pragma unroll
      for (int e = 0; e < 8; ++e) {
        const int kk = 32 * S + 16 * (e >> 2) + 4 * h + (e & 3);
        const int row = 16 * tau + m;
        const float val = __expf(DIR ? trans[kk * KK + row] : trans[row * KK + kk]);
        const f16 hi = (f16)val;
        Ehi[tau][S].e[e] = hi;
        Elo[tau][S].e[e] = (f16)(val - (float)hi);
      }

  const float* fB = feats + (size_t)(grp * GB + m) * TT * KK + 4 * h;

  // ---- feat ring, depth 4 (3 windows of slack)
  f32x4 uR[4][4];
  #pragma unroll
  for (int d = 0; d < 4; ++d) {
    int t = DIR ? (t_hi - 1 - d) : (t_lo + d);
    if (DIR) { if (t < t_lo) t = t_lo; } else { if (t > t_hi) t = t_hi; }
    #pragma unroll
    for (int tau = 0; tau < 4; ++tau)
      uR[d][tau] = *(const f32x4*)(fB + (size_t)t * KK + 16 * tau);
  }

  W8 whi[2], wlo[2];
  f32x4 g[4];
  esum = 0;

  if (DIR == 0) {
    if (one_hot) {
      #pragma unroll
      for (int tau = 0; tau < 4; ++tau) q[tau] = (f32x4){0.f, 0.f, 0.f, 0.f};
      if (h == 3) q[3].z = 1.0f;    // row 62 = 16*3 + 4*3 + 2 (START)
    } else {
      #pragma unroll
      for (int tau = 0; tau < 4; ++tau) q[tau] = (f32x4){1.f, 1.f, 1.f, 1.f};
    }
    pack_w(q, whi, wlo);
  } else {
    f32x4 q0[4];
    #pragma unroll
    for (int tau = 0; tau < 4; ++tau)
      q0[tau] = exp4(*(const f32x4*)(fB + (size_t)t_hi * KK + 16 * tau));
    normalize(q0, q, esum);         // w0 = exp(u_{t_hi}) normalized (init only)
    pack_w(q, whi, wlo);
  }
  #pragma unroll
  for (int tau = 0; tau < 4; ++tau) g[tau] = exp4(uR[0][tau]);

  const int nq = nstep >> 2;
  for (int gg = 0; gg < nq; ++gg) {
    const int j = 4 * gg;
    step_one<DIR, 0>(fB, j + 0, t_lo, t_hi, Ehi, Elo, whi, wlo, uR, g, q, esum, true);
    step_one<DIR, 1>(fB, j + 1, t_lo, t_hi, Ehi, Elo, whi, wlo, uR, g, q, esum, true);
    step_one<DIR, 2>(fB, j + 2, t_lo, t_hi, Ehi, Elo, whi, wlo, uR, g, q, esum, true);
    step_one<DIR, 3>(fB, j + 3, t_lo, t_hi, Ehi, Elo, whi, wlo, uR, g, q, esum, true);
  }
  const int jr = 4 * nq;
  const int rem = nstep & 3;
  if (rem > 0) step_one<DIR, 0>(fB, jr + 0, t_lo, t_hi, Ehi, Elo, whi, wlo, uR, g, q, esum, true);
  if (rem > 1) step_one<DIR, 1>(fB, jr + 1, t_lo, t_hi, Ehi, Elo, whi, wlo, uR, g, q, esum, true);
  if (rem > 2) step_one<DIR, 2>(fB, jr + 2, t_lo, t_hi, Ehi, Elo, whi, wlo, uR, g, q, esum, true);

  if (DIR == 1) {                   // tail: final E^T, no D (gs = s only)
    step_one<DIR, 3>(fB, nstep, t_lo, t_hi, Ehi, Elo, whi, wlo, uR, g, q, esum, false);
  }
}

__global__ void zero_diff_kernel(float* __restrict__ diff) {
  diff[threadIdx.x] = 0.0f;
}

__global__ __launch_bounds__(128, 1) void crf_seg_kernel(
    const float* __restrict__ feats,   // [B, T, K]
    const int*   __restrict__ tags,    // [B, T]
    const float* __restrict__ trans,   // [K, K]  trans[i*K+j] = score j -> i
    float*       __restrict__ diff)    // [B]  forward - gold (accumulated)
{
  __shared__ float ysh[KK][GB];
  __shared__ int   esum_sh[GB];
  __shared__ float gpart[GB];

  const int chainBlocks = 64 * NJ;

  if ((int)blockIdx.x < chainBlocks) {
    // ================= chain block (grp, junction j) =================
    const int lane = threadIdx.x & 63;
    const int wv   = threadIdx.x >> 6;
    const int grp  = blockIdx.x / NJ;        // 0..63 (16 batches each)
    const int j    = 1 + blockIdx.x % NJ;    // junction 1..NJ
    const int m = lane & 15;
    const int h = lane >> 4;

    f32x4 v[4];
    int esum;

    if (wv == 1) {
      // g_{j+1}: bwd over segment j+1 = [SEGLEN*j+1 .. min(SEGLEN*(j+1), 511)]
      const int t_lo = SEGLEN * j + 1;
      const int t_hi = (j == NJ) ? (TT - 1) : SEGLEN * (j + 1);
      run_seg<1>(feats, trans, grp, lane, t_lo, t_hi, t_hi - t_lo, 0, v, esum);
      #pragma unroll
      for (int tau = 0; tau < 4; ++tau) {
        ysh[16 * tau + 4 * h + 0][m] = v[tau].x;
        ysh[16 * tau + 4 * h + 1][m] = v[tau].y;
        ysh[16 * tau + 4 * h + 2][m] = v[tau].z;
        ysh[16 * tau + 4 * h + 3][m] = v[tau].w;
      }
      if (lane < 16) esum_sh[lane] = esum;
      __syncthreads();
    } else {
      // f_j: fwd over segment j; one-hot start iff j==1
      const int t_lo = SEGLEN * (j - 1) + 1;
      const int t_hi = SEGLEN * j;
      run_seg<0>(feats, trans, grp, lane, t_lo, t_hi, SEGLEN, j == 1, v, esum);

      __syncthreads();

      // ---- junction dots: A = g~^T f~ ; Bs = 1^T f~  (per column m)
      float A = 0.f, Bs = 0.f;
      #pragma unroll
      for (int tau = 0; tau < 4; ++tau) {
        A += v[tau].x * ysh[16 * tau + 4 * h + 0][m];
        A += v[tau].y * ysh[16 * tau + 4 * h + 1][m];
        A += v[tau].z * ysh[16 * tau + 4 * h + 2][m];
        A += v[tau].w * ysh[16 * tau + 4 * h + 3][m];
        Bs += (v[tau].x + v[tau].y) + (v[tau].z + v[tau].w);
      }
      A  += __shfl_xor(A, 16);  A  += __shfl_xor(A, 32);
      Bs += __shfl_xor(Bs, 16); Bs += __shfl_xor(Bs, 32);

      if (lane < 16) {
        // c_j = log(A) + (ef+eg)ln2 - [j>1](log(Bs) + ef*ln2)
        float c = __logf(A) + (float)(esum + esum_sh[lane]) * LN2F;
        if (j > 1) c -= __logf(Bs) + (float)esum * LN2F;
        atomicAdd(&diff[grp * GB + lane], c);
      }
    }
  } else {
    // ================= gold block (one per batch-group) =================
    const int grp = blockIdx.x - chainBlocks;
    const int tid = threadIdx.x;
    const int m   = tid & 15;
    const int h8  = tid >> 4;                // 0..7 across both waves
    const int bglob = grp * GB + m;
    const int* tg = tags + bglob * TT;
    const float* fg = feats + (size_t)bglob * TT * KK;

    float gs = 0.f;
    #pragma unroll 8
    for (int tt = 1 + h8; tt < TT; tt += 8) {
      const int tc = tg[tt];
      const int tp = tg[tt - 1];
      gs += trans[tc * KK + tp] + fg[(size_t)tt * KK + tc];
    }
    gs += __shfl_xor(gs, 16);
    gs += __shfl_xor(gs, 32);
    // lanes<16 of each wave hold the per-m sum over its 4 h8 values
    if (tid >= 64 && (tid & 63) < 16) gpart[tid & 15] = gs;
    __syncthreads();
    if (tid < 16) atomicAdd(&diff[grp * GB + tid], -(gs + gpart[tid]));
  }
}

__global__ __launch_bounds__(1024) void reduce_mean_kernel(
    const float* __restrict__ diff, float* __restrict__ out)
{
  __shared__ float part[16];
  const int tid = threadIdx.x;
  float v = diff[tid];
  #pragma unroll
  for (int off = 32; off; off >>= 1) v += __shfl_xor(v, off);
  if ((tid & 63) == 0) part[tid >> 6] = v;
  __syncthreads();
  if (tid < 16) {
    float s = part[tid];
    #pragma unroll
    for (int off = 8; off; off >>= 1) s += __shfl_xor(s, off);
    if (tid == 0) out[0] = s * (1.0f / 1024.0f);
  }
}

extern "C" void kernel_launch(void* const* d_in, const int* in_sizes, int n_in,
                              void* d_out, int out_size, void* d_ws, size_t ws_size,
                              hipStream_t stream) {
  const float* feats = (const float*)d_in[0];
  const int*   tags  = (const int*)d_in[1];
  const float* trans = (const float*)d_in[2];
  float* out  = (float*)d_out;
  float* diff = (float*)d_ws;   // 1024 floats of scratch

  zero_diff_kernel<<<dim3(1), dim3(1024), 0, stream>>>(diff);
  crf_seg_kernel<<<dim3(64 * NJ + 64), dim3(128), 0, stream>>>(feats, tags, trans, diff);
  reduce_mean_kernel<<<dim3(1), dim3(1024), 0, stream>>>(diff, out);
}